// Round 10
// baseline (209.529 us; speedup 1.0000x reference)
//
#include <hip/hip_runtime.h>
#include <hip/hip_fp16.h>
#include <math.h>

#define NN 50000
#define NE 800000
#define INF_ 128
#define HEADS 4
#define OUTF 16
#define HC 64
#define NEG_SLOPE 0.2f
#define NBKT2 ((NN + 63) >> 6)      // 782 buckets of 64 dsts
#define CHA 4096                    // edges per k_binA block
#define NBA ((NE + CHA - 1) / CHA)  // 196
#define CAPE 2048                   // max edges sorted in LDS per bucket
#define XPAD 136

typedef _Float16 half8 __attribute__((ext_vector_type(8)));
typedef float f32x4 __attribute__((ext_vector_type(4)));

__device__ __forceinline__ unsigned short h2u(float f) {
    __half h = __float2half(f);
    return *(unsigned short*)&h;
}
__device__ __forceinline__ float u2f(unsigned short u) {
    __half h = *(__half*)&u;
    return __half2float(h);
}
__device__ __forceinline__ float lrelu(float v) {
    return v > 0.f ? v : NEG_SLOPE * v;
}

// ---------- K2: xw = x @ W via MFMA fp16 + per-node logits ----------
__global__ __launch_bounds__(256) void k_xw(
    const float* __restrict__ x, const float* __restrict__ W,
    const float* __restrict__ att_src, const float* __restrict__ att_dst,
    unsigned short* __restrict__ xw16, unsigned short* __restrict__ a_src16,
    float* __restrict__ a_dst) {
    __shared__ _Float16 sxh[64][XPAD];
    __shared__ _Float16 sWT[64][XPAD];
    int t = threadIdx.x;
    int n0 = blockIdx.x * 64;
    for (int i = t; i < 64 * 32; i += 256) {
        int r = i >> 5, c4 = (i & 31) * 4;
        int n = n0 + r;
        float4 v = (n < NN) ? *(const float4*)&x[(size_t)n * INF_ + c4]
                            : make_float4(0.f, 0.f, 0.f, 0.f);
        sxh[r][c4 + 0] = (_Float16)v.x;
        sxh[r][c4 + 1] = (_Float16)v.y;
        sxh[r][c4 + 2] = (_Float16)v.z;
        sxh[r][c4 + 3] = (_Float16)v.w;
    }
    for (int i = t; i < INF_ * HC; i += 256) {
        int k = i >> 6, c = i & 63;
        sWT[c][k] = (_Float16)W[i];
    }
    __syncthreads();
    int w = t >> 6, l = t & 63;
    int lr = l & 15, kg = l >> 4;
    f32x4 acc0 = {0.f,0.f,0.f,0.f}, acc1 = acc0, acc2 = acc0, acc3 = acc0;
#pragma unroll
    for (int kk = 0; kk < 4; ++kk) {
        half8 a = *(half8*)&sxh[w * 16 + lr][kk * 32 + kg * 8];
        half8 b0 = *(half8*)&sWT[0 * 16 + lr][kk * 32 + kg * 8];
        half8 b1 = *(half8*)&sWT[1 * 16 + lr][kk * 32 + kg * 8];
        half8 b2 = *(half8*)&sWT[2 * 16 + lr][kk * 32 + kg * 8];
        half8 b3 = *(half8*)&sWT[3 * 16 + lr][kk * 32 + kg * 8];
        acc0 = __builtin_amdgcn_mfma_f32_16x16x32_f16(a, b0, acc0, 0, 0, 0);
        acc1 = __builtin_amdgcn_mfma_f32_16x16x32_f16(a, b1, acc1, 0, 0, 0);
        acc2 = __builtin_amdgcn_mfma_f32_16x16x32_f16(a, b2, acc2, 0, 0, 0);
        acc3 = __builtin_amdgcn_mfma_f32_16x16x32_f16(a, b3, acc3, 0, 0, 0);
    }
    float attS[4], attD[4];
#pragma unroll
    for (int ct = 0; ct < 4; ++ct) {
        attS[ct] = att_src[ct * 16 + lr];
        attD[ct] = att_dst[ct * 16 + lr];
    }
    int rbase = n0 + w * 16 + kg * 4;
    f32x4 accs[4] = {acc0, acc1, acc2, acc3};
#pragma unroll
    for (int ct = 0; ct < 4; ++ct) {
#pragma unroll
        for (int j = 0; j < 4; ++j) {
            float c = accs[ct][j];
            int node = rbase + j;
            if (node < NN)
                xw16[(size_t)node * HC + ct * 16 + lr] = h2u(c);
            float vs = c * attS[ct];
            float vd = c * attD[ct];
#pragma unroll
            for (int m = 1; m < 16; m <<= 1) {
                vs += __shfl_xor(vs, m);
                vd += __shfl_xor(vd, m);
            }
            if (lr == 0 && node < NN) {
                a_src16[node * HEADS + ct] = h2u(vs);
                a_dst[node * HEADS + ct] = vd;
            }
        }
    }
}

// ---------- coarse histogram (dst >> 6) ----------
__global__ __launch_bounds__(256) void k_coarse(const int* __restrict__ ei,
                                                int* __restrict__ ccnt) {
    __shared__ int lh[NBKT2];
    int t = threadIdx.x;
    for (int i = t; i < NBKT2; i += 256) lh[i] = 0;
    __syncthreads();
    for (int i = blockIdx.x * 256 + t; i < NE; i += gridDim.x * 256)
        atomicAdd(&lh[ei[NE + i] >> 6], 1);
    __syncthreads();
    for (int i = t; i < NBKT2; i += 256)
        if (lh[i]) atomicAdd(&ccnt[i], lh[i]);
}

// ---------- scan bucket counts (4 bins/thread) ----------
__global__ void k_scanb(const int* __restrict__ ccnt, int* __restrict__ boff,
                        int* __restrict__ ccur) {
    __shared__ int sd[256];
    int t = threadIdx.x;
    int b4 = t * 4;
    int c[4], pre[4];
#pragma unroll
    for (int j = 0; j < 4; ++j)
        c[j] = (b4 + j < NBKT2) ? ccnt[b4 + j] : 0;
    pre[0] = 0;
#pragma unroll
    for (int j = 1; j < 4; ++j) pre[j] = pre[j - 1] + c[j - 1];
    int tot = pre[3] + c[3];
    sd[t] = tot; __syncthreads();
    for (int o = 1; o < 256; o <<= 1) {
        int a = (t >= o) ? sd[t - o] : 0;
        __syncthreads();
        sd[t] += a;
        __syncthreads();
    }
    int ex = sd[t] - tot;
#pragma unroll
    for (int j = 0; j < 4; ++j)
        if (b4 + j < NBKT2) { boff[b4 + j] = ex + pre[j]; ccur[b4 + j] = ex + pre[j]; }
    if (t == 255) boff[NBKT2] = sd[255];
}

// ---------- pass A: bin edges into coarse buckets ----------
__global__ __launch_bounds__(256) void k_binA(const int* __restrict__ ei,
                                              const float* __restrict__ ea,
                                              int* __restrict__ ccur,
                                              uint2* __restrict__ ebuf) {
    __shared__ int lh[NBKT2], lcur[NBKT2];
    int t = threadIdx.x;
    int e0 = blockIdx.x * CHA;
    int ecnt = NE - e0; if (ecnt > CHA) ecnt = CHA;
    for (int i = t; i < NBKT2; i += 256) lh[i] = 0;
    __syncthreads();
    if (ecnt == CHA) {
        int dl[16];
#pragma unroll
        for (int j = 0; j < 16; ++j) {
            dl[j] = ei[NE + e0 + t + j * 256];
            atomicAdd(&lh[dl[j] >> 6], 1);
        }
        __syncthreads();
        for (int i = t; i < NBKT2; i += 256)
            lcur[i] = lh[i] ? atomicAdd(&ccur[i], lh[i]) : 0;
        __syncthreads();
#pragma unroll
        for (int j = 0; j < 16; ++j) {
            int e = e0 + t + j * 256;
            int dst = dl[j];
            int p = atomicAdd(&lcur[dst >> 6], 1);
            uint2 pk;
            pk.x = (unsigned)ei[e] | ((unsigned)(dst & 63) << 16);
            pk.y = __float_as_uint(ea[e]);
            ebuf[p] = pk;
        }
    } else {
        for (int i = t; i < ecnt; i += 256)
            atomicAdd(&lh[ei[NE + e0 + i] >> 6], 1);
        __syncthreads();
        for (int i = t; i < NBKT2; i += 256)
            lcur[i] = lh[i] ? atomicAdd(&ccur[i], lh[i]) : 0;
        __syncthreads();
        for (int i = t; i < ecnt; i += 256) {
            int e = e0 + i;
            int dst = ei[NE + e];
            int p = atomicAdd(&lcur[dst >> 6], 1);
            uint2 pk;
            pk.x = (unsigned)ei[e] | ((unsigned)(dst & 63) << 16);
            pk.y = __float_as_uint(ea[e]);
            ebuf[p] = pk;
        }
    }
}

// ---------- fused binB + gather: sort bucket in LDS, then flash-gather ----------
__global__ __launch_bounds__(256) void k_gfuse(
    const int* __restrict__ boff, const uint2* __restrict__ ebuf,
    const unsigned short* __restrict__ a_src16, const float* __restrict__ a_dst,
    const unsigned short* __restrict__ xw16,
    const float* __restrict__ W_edge, const float* __restrict__ att_edge,
    const float* __restrict__ bias, float* __restrict__ out) {
    __shared__ __align__(16) float sce[4];
    __shared__ unsigned sedge[CAPE + 16];          // src16 | ea_fp16<<16, sorted
    __shared__ int lh[64], lofs[64], lcur[64];
    __shared__ __align__(16) float ldsP[4][16][4];
    __shared__ int ldsS[4][16];
    int t = threadIdx.x;
    if (t < 4) {
        float s_ = 0.f;
        for (int k = 0; k < OUTF; ++k)
            s_ = fmaf(W_edge[t * OUTF + k], att_edge[t * OUTF + k], s_);
        sce[t] = s_;
    }
    if (t < 64) lh[t] = 0;
    __syncthreads();

    int b = blockIdx.x;
    int base = boff[b];
    int cntb = boff[b + 1] - base;
    int w = t >> 6, lane = t & 63;
    int e16 = lane & 15, hA = lane >> 4;
    int l32 = lane & 31, g = lane >> 5;
    int c2 = l32 * 2, h2 = l32 >> 3;
    float ceA = sce[hA];

    if (cntb <= CAPE) {
        // ---- sort bucket into LDS ----
        uint2 held[8];
#pragma unroll
        for (int j = 0; j < 8; ++j) {
            int i = t + j * 256;
            if (i < cntb) {
                held[j] = ebuf[base + i];
                atomicAdd(&lh[held[j].x >> 16], 1);
            }
        }
        __syncthreads();
        if (t < 64) {
            int v = lh[t], xx = v;
#pragma unroll
            for (int o = 1; o < 64; o <<= 1) {
                int nn_ = __shfl_up(xx, o);
                if (lane >= o) xx += nn_;
            }
            lofs[t] = xx - v; lcur[t] = xx - v;
        }
        __syncthreads();
#pragma unroll
        for (int j = 0; j < 8; ++j) {
            int i = t + j * 256;
            if (i < cntb) {
                uint2 pk = held[j];
                int d = pk.x >> 16;
                int p = atomicAdd(&lcur[d], 1);
                sedge[p] = (pk.x & 0xFFFFu) |
                           ((unsigned)h2u(__uint_as_float(pk.y)) << 16);
            }
        }
        __syncthreads();
        // ---- per-wave: 16 nodes each, straight from LDS ----
        for (int q = 0; q < 16; ++q) {
            int dl_ = (w << 4) + q;
            int n = (b << 6) + dl_;
            if (n >= NN) continue;
            int rs = lofs[dl_], rl = lh[dl_];
            float adA = a_dst[n * 4 + hA];
            float s = 0.f, a0 = 0.f, a1 = 0.f, easum = 0.f;
            int nch = (rl + 15) >> 4;
            for (int ch = 0; ch < nch; ++ch) {
                int cbase = rs + (ch << 4);
                int cc = rl - (ch << 4); if (cc > 16) cc = 16;
                bool valid = e16 < cc;
                unsigned se = sedge[cbase + e16];
                int srci = se & 0xFFFFu;
                float eav = u2f((unsigned short)(se >> 16));
                float asv = u2f(a_src16[srci * 4 + hA]);
                float p = 0.f, es = 0.f;
                if (valid) {
                    p = __expf(lrelu(asv + adA + eav * ceA));
                    es = eav;
                }
#pragma unroll
                for (int mm = 1; mm < 16; mm <<= 1) es += __shfl_xor(es, mm);
                easum += es;
                ldsP[w][e16][hA] = p;
                if (hA == 0) ldsS[w][e16] = srci;
                asm volatile("s_waitcnt lgkmcnt(0)" ::: "memory");
                __builtin_amdgcn_sched_barrier(0);
#pragma unroll 4
                for (int i = 0; i < cc; i += 2) {
                    int ii = i + g;
                    if (ii < cc) {
                        float pv = ldsP[w][ii][h2];
                        int si = ldsS[w][ii];
                        unsigned xv = *(const unsigned*)&xw16[(size_t)si * HC + c2];
                        s += pv;
                        a0 = fmaf(pv, u2f((unsigned short)(xv & 0xFFFFu)), a0);
                        a1 = fmaf(pv, u2f((unsigned short)(xv >> 16)), a1);
                    }
                }
                asm volatile("s_waitcnt lgkmcnt(0)" ::: "memory");
                __builtin_amdgcn_sched_barrier(0);
            }
            s  += __shfl_xor(s, 32);
            a0 += __shfl_xor(a0, 32);
            a1 += __shfl_xor(a1, 32);
            float adB = a_dst[n * 4 + h2];
            float asnB = u2f(a_src16[n * 4 + h2]);
            float eavm = easum / fmaxf((float)rl, 1.f);
            float pp = __expf(lrelu(asnB + adB + eavm * sce[h2]));
            unsigned xs = *(const unsigned*)&xw16[(size_t)n * HC + c2];
            s += pp;
            a0 = fmaf(pp, u2f((unsigned short)(xs & 0xFFFFu)), a0);
            a1 = fmaf(pp, u2f((unsigned short)(xs >> 16)), a1);
            if (g == 0) {
                float2 o;
                o.x = fmaxf(a0 / s + bias[c2], 0.f);
                o.y = fmaxf(a1 / s + bias[c2 + 1], 0.f);
                *(float2*)&out[(size_t)n * HC + c2] = o;
            }
        }
    } else {
        // ---- fallback (bucket too big for LDS; correct but slow, not expected) ----
        for (int q = 0; q < 16; ++q) {
            int dl_ = (w << 4) + q;
            int n = (b << 6) + dl_;
            if (n >= NN) continue;
            float adA = a_dst[n * 4 + hA];
            float s = 0.f, a0 = 0.f, a1 = 0.f, easum = 0.f;
            int deg = 0;
            int nch = (cntb + 15) >> 4;
            for (int ch = 0; ch < nch; ++ch) {
                int cbase = base + (ch << 4);
                int cc = cntb - (ch << 4); if (cc > 16) cc = 16;
                bool valid = e16 < cc;
                uint2 pk = valid ? ebuf[cbase + e16] : make_uint2(0u, 0u);
                bool mine = valid && ((int)(pk.x >> 16) == dl_);
                int srci = pk.x & 0xFFFFu;
                float eav = __uint_as_float(pk.y);
                float asv = u2f(a_src16[srci * 4 + hA]);
                float p = 0.f, es = 0.f; int dd = 0;
                if (mine) {
                    p = __expf(lrelu(asv + adA + eav * ceA));
                    es = eav; dd = 1;
                }
#pragma unroll
                for (int mm = 1; mm < 16; mm <<= 1) {
                    es += __shfl_xor(es, mm);
                    dd += __shfl_xor(dd, mm);
                }
                easum += es; deg += dd;
                ldsP[w][e16][hA] = p;
                if (hA == 0) ldsS[w][e16] = srci;
                asm volatile("s_waitcnt lgkmcnt(0)" ::: "memory");
                __builtin_amdgcn_sched_barrier(0);
#pragma unroll 4
                for (int i = 0; i < cc; i += 2) {
                    int ii = i + g;
                    if (ii < cc) {
                        float pv = ldsP[w][ii][h2];
                        int si = ldsS[w][ii];
                        unsigned xv = *(const unsigned*)&xw16[(size_t)si * HC + c2];
                        s += pv;
                        a0 = fmaf(pv, u2f((unsigned short)(xv & 0xFFFFu)), a0);
                        a1 = fmaf(pv, u2f((unsigned short)(xv >> 16)), a1);
                    }
                }
                asm volatile("s_waitcnt lgkmcnt(0)" ::: "memory");
                __builtin_amdgcn_sched_barrier(0);
            }
            s  += __shfl_xor(s, 32);
            a0 += __shfl_xor(a0, 32);
            a1 += __shfl_xor(a1, 32);
            float adB = a_dst[n * 4 + h2];
            float asnB = u2f(a_src16[n * 4 + h2]);
            float eavm = easum / fmaxf((float)deg, 1.f);
            float pp = __expf(lrelu(asnB + adB + eavm * sce[h2]));
            unsigned xs = *(const unsigned*)&xw16[(size_t)n * HC + c2];
            s += pp;
            a0 = fmaf(pp, u2f((unsigned short)(xs & 0xFFFFu)), a0);
            a1 = fmaf(pp, u2f((unsigned short)(xs >> 16)), a1);
            if (g == 0) {
                float2 o;
                o.x = fmaxf(a0 / s + bias[c2], 0.f);
                o.y = fmaxf(a1 / s + bias[c2 + 1], 0.f);
                *(float2*)&out[(size_t)n * HC + c2] = o;
            }
        }
    }
}

extern "C" void kernel_launch(void* const* d_in, const int* in_sizes, int n_in,
                              void* d_out, int out_size, void* d_ws, size_t ws_size,
                              hipStream_t stream) {
    const float* x        = (const float*)d_in[0];
    const int*   ei       = (const int*)d_in[1];
    const float* ea       = (const float*)d_in[2];
    const float* W        = (const float*)d_in[3];
    const float* W_edge   = (const float*)d_in[4];
    const float* att_src  = (const float*)d_in[5];
    const float* att_dst  = (const float*)d_in[6];
    const float* att_edge = (const float*)d_in[7];
    const float* bias     = (const float*)d_in[8];
    float* out = (float*)d_out;

    float* ws = (float*)d_ws;
    unsigned short* xw16    = (unsigned short*)ws;              // 64N halves
    uint2* ebuf   = (uint2*)(ws + (size_t)32 * NN);             // E uint2
    unsigned short* a_src16 = (unsigned short*)(ebuf + NE);     // 4N halves
    float* a_dst  = (float*)(a_src16 + (size_t)HEADS * NN);     // 4N floats
    int*   ccnt   = (int*)(a_dst + (size_t)HEADS * NN);         // NBKT2
    int*   ccur   = ccnt + NBKT2;                               // NBKT2
    int*   boff   = ccur + NBKT2;                               // NBKT2+1

    hipMemsetAsync(ccnt, 0, NBKT2 * sizeof(int), stream);
    k_coarse<<<256, 256, 0, stream>>>(ei, ccnt);
    k_scanb<<<1, 256, 0, stream>>>(ccnt, boff, ccur);
    k_binA<<<NBA, 256, 0, stream>>>(ei, ea, ccur, ebuf);
    k_xw<<<(NN + 63) / 64, 256, 0, stream>>>(x, W, att_src, att_dst, xw16, a_src16, a_dst);
    k_gfuse<<<NBKT2, 256, 0, stream>>>(
        boff, ebuf, a_src16, a_dst, xw16, W_edge, att_edge, bias, out);
}

// Round 11
// 165.729 us; speedup vs baseline: 1.2643x; 1.2643x over previous
//
#include <hip/hip_runtime.h>
#include <hip/hip_fp16.h>
#include <math.h>

#define NN 50000
#define NE 800000
#define INF_ 128
#define HEADS 4
#define OUTF 16
#define HC 64
#define NEG_SLOPE 0.2f
#define NBKT 196            // buckets of 256 dsts
#define CAP 5120            // region capacity per bucket (mean 4082, 16-sigma slack)
#define CHA 4096            // edges per k_binA block
#define NBA ((NE + CHA - 1) / CHA)
#define WPB 4               // waves per block in gather
#define XPAD 136

typedef _Float16 half8 __attribute__((ext_vector_type(8)));
typedef float f32x4 __attribute__((ext_vector_type(4)));

__device__ __forceinline__ unsigned short h2u(float f) {
    __half h = __float2half(f);
    return *(unsigned short*)&h;
}
__device__ __forceinline__ float u2f(unsigned short u) {
    __half h = *(__half*)&u;
    return __half2float(h);
}
__device__ __forceinline__ float lrelu(float v) {
    return v > 0.f ? v : NEG_SLOPE * v;
}

// ---------- K2: xw = x @ W via MFMA fp16 + per-node logits ----------
__global__ __launch_bounds__(256) void k_xw(
    const float* __restrict__ x, const float* __restrict__ W,
    const float* __restrict__ att_src, const float* __restrict__ att_dst,
    unsigned short* __restrict__ xw16, unsigned short* __restrict__ a_src16,
    float* __restrict__ a_dst) {
    __shared__ _Float16 sxh[64][XPAD];
    __shared__ _Float16 sWT[64][XPAD];
    int t = threadIdx.x;
    int n0 = blockIdx.x * 64;
    for (int i = t; i < 64 * 32; i += 256) {
        int r = i >> 5, c4 = (i & 31) * 4;
        int n = n0 + r;
        float4 v = (n < NN) ? *(const float4*)&x[(size_t)n * INF_ + c4]
                            : make_float4(0.f, 0.f, 0.f, 0.f);
        sxh[r][c4 + 0] = (_Float16)v.x;
        sxh[r][c4 + 1] = (_Float16)v.y;
        sxh[r][c4 + 2] = (_Float16)v.z;
        sxh[r][c4 + 3] = (_Float16)v.w;
    }
    for (int i = t; i < INF_ * HC; i += 256) {
        int k = i >> 6, c = i & 63;
        sWT[c][k] = (_Float16)W[i];
    }
    __syncthreads();
    int w = t >> 6, l = t & 63;
    int lr = l & 15, kg = l >> 4;
    f32x4 acc0 = {0.f,0.f,0.f,0.f}, acc1 = acc0, acc2 = acc0, acc3 = acc0;
#pragma unroll
    for (int kk = 0; kk < 4; ++kk) {
        half8 a = *(half8*)&sxh[w * 16 + lr][kk * 32 + kg * 8];
        half8 b0 = *(half8*)&sWT[0 * 16 + lr][kk * 32 + kg * 8];
        half8 b1 = *(half8*)&sWT[1 * 16 + lr][kk * 32 + kg * 8];
        half8 b2 = *(half8*)&sWT[2 * 16 + lr][kk * 32 + kg * 8];
        half8 b3 = *(half8*)&sWT[3 * 16 + lr][kk * 32 + kg * 8];
        acc0 = __builtin_amdgcn_mfma_f32_16x16x32_f16(a, b0, acc0, 0, 0, 0);
        acc1 = __builtin_amdgcn_mfma_f32_16x16x32_f16(a, b1, acc1, 0, 0, 0);
        acc2 = __builtin_amdgcn_mfma_f32_16x16x32_f16(a, b2, acc2, 0, 0, 0);
        acc3 = __builtin_amdgcn_mfma_f32_16x16x32_f16(a, b3, acc3, 0, 0, 0);
    }
    float attS[4], attD[4];
#pragma unroll
    for (int ct = 0; ct < 4; ++ct) {
        attS[ct] = att_src[ct * 16 + lr];
        attD[ct] = att_dst[ct * 16 + lr];
    }
    int rbase = n0 + w * 16 + kg * 4;
    f32x4 accs[4] = {acc0, acc1, acc2, acc3};
#pragma unroll
    for (int ct = 0; ct < 4; ++ct) {
#pragma unroll
        for (int j = 0; j < 4; ++j) {
            float c = accs[ct][j];
            int node = rbase + j;
            if (node < NN)
                xw16[(size_t)node * HC + ct * 16 + lr] = h2u(c);
            float vs = c * attS[ct];
            float vd = c * attD[ct];
#pragma unroll
            for (int m = 1; m < 16; m <<= 1) {
                vs += __shfl_xor(vs, m);
                vd += __shfl_xor(vd, m);
            }
            if (lr == 0 && node < NN) {
                a_src16[node * HEADS + ct] = h2u(vs);
                a_dst[node * HEADS + ct] = vd;
            }
        }
    }
}

// ---------- pass A: bin edges into fixed per-bucket regions (no scan) ----------
__global__ __launch_bounds__(256) void k_binA(const int* __restrict__ ei,
                                              const float* __restrict__ ea,
                                              int* __restrict__ ccur,
                                              uint2* __restrict__ ebuf) {
    __shared__ int lh[NBKT], lcur[NBKT];
    int t = threadIdx.x;
    int e0 = blockIdx.x * CHA;
    int ecnt = NE - e0; if (ecnt > CHA) ecnt = CHA;
    for (int i = t; i < NBKT; i += 256) lh[i] = 0;
    __syncthreads();
    if (ecnt == CHA) {
        int dl[16];
#pragma unroll
        for (int j = 0; j < 16; ++j) {
            dl[j] = ei[NE + e0 + t + j * 256];
            atomicAdd(&lh[dl[j] >> 8], 1);
        }
        __syncthreads();
        for (int i = t; i < NBKT; i += 256)
            lcur[i] = lh[i] ? (i * CAP + atomicAdd(&ccur[i], lh[i])) : 0;
        __syncthreads();
#pragma unroll
        for (int j = 0; j < 16; ++j) {
            int e = e0 + t + j * 256;
            int dst = dl[j];
            int b = dst >> 8;
            int p = atomicAdd(&lcur[b], 1);
            if (p < (b + 1) * CAP) {
                uint2 pk;
                pk.x = (unsigned)ei[e] | ((unsigned)(dst & 255) << 16);
                pk.y = __float_as_uint(ea[e]);
                ebuf[p] = pk;
            }
        }
    } else {
        for (int i = t; i < ecnt; i += 256)
            atomicAdd(&lh[ei[NE + e0 + i] >> 8], 1);
        __syncthreads();
        for (int i = t; i < NBKT; i += 256)
            lcur[i] = lh[i] ? (i * CAP + atomicAdd(&ccur[i], lh[i])) : 0;
        __syncthreads();
        for (int i = t; i < ecnt; i += 256) {
            int e = e0 + i;
            int dst = ei[NE + e];
            int b = dst >> 8;
            int p = atomicAdd(&lcur[b], 1);
            if (p < (b + 1) * CAP) {
                uint2 pk;
                pk.x = (unsigned)ei[e] | ((unsigned)(dst & 255) << 16);
                pk.y = __float_as_uint(ea[e]);
                ebuf[p] = pk;
            }
        }
    }
}

// ---------- pass B: per-dst sort within bucket region + edge_attr sum ----------
__global__ __launch_bounds__(256) void k_binB(const int* __restrict__ ccur,
                                              const uint2* __restrict__ ebuf,
                                              unsigned* __restrict__ esort,
                                              int* __restrict__ deg,
                                              int* __restrict__ offs,
                                              float* __restrict__ easum) {
    __shared__ int lh[256], lcur[256], sd[256];
    __shared__ float lsum[256];
    int t = threadIdx.x;
    int b = blockIdx.x;
    int base = b * CAP;
    int cnt = ccur[b]; if (cnt > CAP) cnt = CAP;
    lh[t] = 0;
    lsum[t] = 0.f;
    __syncthreads();
    for (int i = t; i < cnt; i += 256)
        atomicAdd(&lh[(ebuf[base + i].x >> 16) & 255], 1);
    __syncthreads();
    int v = lh[t];
    sd[t] = v; __syncthreads();
    for (int o = 1; o < 256; o <<= 1) {
        int a = (t >= o) ? sd[t - o] : 0;
        __syncthreads();
        sd[t] += a;
        __syncthreads();
    }
    int ex = sd[t] - v;
    lcur[t] = ex;
    __syncthreads();
    for (int i = t; i < cnt; i += 256) {
        uint2 pk = ebuf[base + i];
        int d = (pk.x >> 16) & 255;
        int p = atomicAdd(&lcur[d], 1);
        atomicAdd(&lsum[d], __uint_as_float(pk.y));
        esort[base + p] = (pk.x & 0xFFFFu) |
                          ((unsigned)h2u(__uint_as_float(pk.y)) << 16);
    }
    __syncthreads();
    int n = (b << 8) + t;
    if (n < NN) { deg[n] = v; offs[n] = base + ex; easum[n] = lsum[t]; }
}

// ---------- K4: gather — 16-edge chunks, LDS handoff, no max-shift ----------
__global__ __launch_bounds__(256) void k_gather(
    const unsigned* __restrict__ esort, const int* __restrict__ offs,
    const int* __restrict__ deg, const float* __restrict__ easum,
    const unsigned short* __restrict__ a_src16, const float* __restrict__ a_dst,
    const unsigned short* __restrict__ xw16,
    const float* __restrict__ W_edge, const float* __restrict__ att_edge,
    const float* __restrict__ bias, float* __restrict__ out) {
    __shared__ __align__(16) float sce[4];
    __shared__ __align__(16) float ldsP[WPB][16][4];
    __shared__ int ldsS[WPB][16];
    int t = threadIdx.x;
    if (t < 4) {
        float s_ = 0.f;
        for (int k = 0; k < OUTF; ++k)
            s_ = fmaf(W_edge[t * OUTF + k], att_edge[t * OUTF + k], s_);
        sce[t] = s_;
    }
    __syncthreads();
    int lane = t & 63;
    int wslot = t >> 6;
    int n = (blockIdx.x << 2) + wslot;   // grid = NN/4 exactly
    int e16 = lane & 15;
    int h = lane >> 4;

    float ceh = sce[h];
    float adh = a_dst[n * HEADS + h];
    int start = offs[n];
    int cnt = deg[n];

    float s = 0.f, acc = 0.f;

    int nch = (cnt + 15) >> 4;
    for (int ch = 0; ch < nch; ++ch) {
        int base = start + (ch << 4);
        int cc = cnt - (ch << 4); if (cc > 16) cc = 16;
        bool valid = e16 < cc;
        unsigned se = esort[base + e16];   // overread stays inside region (safe)
        int srci = (int)(se & 0xFFFFu);
        float eav = u2f((unsigned short)(se >> 16));
        float asv = u2f(a_src16[srci * HEADS + h]);
        float p = 0.f;
        if (valid) p = __expf(lrelu(asv + adh + eav * ceh));
        ldsP[wslot][e16][h] = p;
        if (h == 0) ldsS[wslot][e16] = srci;
        asm volatile("s_waitcnt lgkmcnt(0)" ::: "memory");
        __builtin_amdgcn_sched_barrier(0);
#pragma unroll 4
        for (int i = 0; i < cc; ++i) {
            float pv = ldsP[wslot][i][h];
            int si = ldsS[wslot][i];
            float xv = u2f(xw16[(size_t)si * HC + lane]);
            s += pv;
            acc = fmaf(pv, xv, acc);
        }
        asm volatile("s_waitcnt lgkmcnt(0)" ::: "memory");
        __builtin_amdgcn_sched_barrier(0);
    }
    // self-loop (fill_value='mean'); easum in fp32 from binB
    float asn = u2f(a_src16[n * HEADS + h]);
    float eavm = easum[n] / fmaxf((float)cnt, 1.f);
    float p = __expf(lrelu(asn + adh + eavm * ceh));
    float xself = u2f(xw16[(size_t)n * HC + lane]);
    s += p;
    acc = fmaf(p, xself, acc);
    out[(size_t)n * HC + lane] = fmaxf(acc / s + bias[lane], 0.f);
}

extern "C" void kernel_launch(void* const* d_in, const int* in_sizes, int n_in,
                              void* d_out, int out_size, void* d_ws, size_t ws_size,
                              hipStream_t stream) {
    const float* x        = (const float*)d_in[0];
    const int*   ei       = (const int*)d_in[1];
    const float* ea       = (const float*)d_in[2];
    const float* W        = (const float*)d_in[3];
    const float* W_edge   = (const float*)d_in[4];
    const float* att_src  = (const float*)d_in[5];
    const float* att_dst  = (const float*)d_in[6];
    const float* att_edge = (const float*)d_in[7];
    const float* bias     = (const float*)d_in[8];
    float* out = (float*)d_out;

    float* ws = (float*)d_ws;
    unsigned short* xw16    = (unsigned short*)ws;              // 64N halves
    uint2* ebuf   = (uint2*)(ws + (size_t)32 * NN);             // NBKT*CAP uint2 (8MB)
    unsigned* esort = (unsigned*)(ebuf + (size_t)NBKT * CAP + 64);  // NBKT*CAP u32 (4MB)
    unsigned short* a_src16 = (unsigned short*)(esort + (size_t)NBKT * CAP + 64);
    float* a_dst  = (float*)(a_src16 + (size_t)HEADS * NN);     // 4N floats
    int*   deg    = (int*)(a_dst + (size_t)HEADS * NN);         // N
    int*   offs   = deg + NN;                                   // N
    float* easum  = (float*)(offs + NN);                        // N
    int*   ccur   = (int*)(easum + NN);                         // NBKT

    hipMemsetAsync(ccur, 0, NBKT * sizeof(int), stream);
    k_binA<<<NBA, 256, 0, stream>>>(ei, ea, ccur, ebuf);
    k_binB<<<NBKT, 256, 0, stream>>>(ccur, ebuf, esort, deg, offs, easum);
    k_xw<<<(NN + 63) / 64, 256, 0, stream>>>(x, W, att_src, att_dst, xw16, a_src16, a_dst);
    k_gather<<<NN / 4, 256, 0, stream>>>(
        esort, offs, deg, easum, a_src16, a_dst, xw16, W_edge, att_edge, bias, out);
}

// Round 12
// 162.330 us; speedup vs baseline: 1.2908x; 1.0209x over previous
//
#include <hip/hip_runtime.h>
#include <hip/hip_fp16.h>
#include <math.h>

#define NN 50000
#define NE 800000
#define INF_ 128
#define HEADS 4
#define OUTF 16
#define HC 64
#define NEG_SLOPE 0.2f
#define NBKT 196            // buckets of 256 dsts
#define CAP 5120            // region capacity per bucket (mean 4082, 16-sigma slack)
#define CHA 4096            // edges per binA block
#define NBA ((NE + CHA - 1) / CHA)      // 196
#define NXW ((NN + 63) / 64)            // 782
#define WPB 4               // waves per block in gather
#define XPAD 136

typedef _Float16 half8 __attribute__((ext_vector_type(8)));
typedef float f32x4 __attribute__((ext_vector_type(4)));

__device__ __forceinline__ unsigned short h2u(float f) {
    __half h = __float2half(f);
    return *(unsigned short*)&h;
}
__device__ __forceinline__ float u2f(unsigned short u) {
    __half h = *(__half*)&u;
    return __half2float(h);
}
__device__ __forceinline__ float lrelu(float v) {
    return v > 0.f ? v : NEG_SLOPE * v;
}

// ---------- fused: binA (blocks 0..NBA-1)  ||  xw MFMA (blocks NBA..NBA+NXW-1) ----------
__global__ __launch_bounds__(256) void k_binA_xw(
    const int* __restrict__ ei, const float* __restrict__ ea,
    int* __restrict__ ccur, uint2* __restrict__ ebuf,
    const float* __restrict__ x, const float* __restrict__ W,
    const float* __restrict__ att_src, const float* __restrict__ att_dst,
    unsigned short* __restrict__ xw16, unsigned short* __restrict__ a_src16,
    float* __restrict__ a_dst) {
    __shared__ int lh[NBKT], lcur[NBKT];
    __shared__ _Float16 sxh[64][XPAD];
    __shared__ _Float16 sWT[64][XPAD];
    int t = threadIdx.x;
    if (blockIdx.x < NBA) {
        // ================= binA =================
        int e0 = blockIdx.x * CHA;
        int ecnt = NE - e0; if (ecnt > CHA) ecnt = CHA;
        for (int i = t; i < NBKT; i += 256) lh[i] = 0;
        __syncthreads();
        if (ecnt == CHA) {
            int dl[16];
#pragma unroll
            for (int j = 0; j < 16; ++j) {
                dl[j] = ei[NE + e0 + t + j * 256];
                atomicAdd(&lh[dl[j] >> 8], 1);
            }
            __syncthreads();
            for (int i = t; i < NBKT; i += 256)
                lcur[i] = lh[i] ? (i * CAP + atomicAdd(&ccur[i], lh[i])) : 0;
            __syncthreads();
#pragma unroll
            for (int j = 0; j < 16; ++j) {
                int e = e0 + t + j * 256;
                int dst = dl[j];
                int b = dst >> 8;
                int p = atomicAdd(&lcur[b], 1);
                if (p < (b + 1) * CAP) {
                    uint2 pk;
                    pk.x = (unsigned)ei[e] | ((unsigned)(dst & 255) << 16);
                    pk.y = __float_as_uint(ea[e]);
                    ebuf[p] = pk;
                }
            }
        } else {
            for (int i = t; i < ecnt; i += 256)
                atomicAdd(&lh[ei[NE + e0 + i] >> 8], 1);
            __syncthreads();
            for (int i = t; i < NBKT; i += 256)
                lcur[i] = lh[i] ? (i * CAP + atomicAdd(&ccur[i], lh[i])) : 0;
            __syncthreads();
            for (int i = t; i < ecnt; i += 256) {
                int e = e0 + i;
                int dst = ei[NE + e];
                int b = dst >> 8;
                int p = atomicAdd(&lcur[b], 1);
                if (p < (b + 1) * CAP) {
                    uint2 pk;
                    pk.x = (unsigned)ei[e] | ((unsigned)(dst & 255) << 16);
                    pk.y = __float_as_uint(ea[e]);
                    ebuf[p] = pk;
                }
            }
        }
        return;
    }
    // ================= xw (MFMA) =================
    int n0 = (blockIdx.x - NBA) * 64;
    for (int i = t; i < 64 * 32; i += 256) {
        int r = i >> 5, c4 = (i & 31) * 4;
        int n = n0 + r;
        float4 v = (n < NN) ? *(const float4*)&x[(size_t)n * INF_ + c4]
                            : make_float4(0.f, 0.f, 0.f, 0.f);
        sxh[r][c4 + 0] = (_Float16)v.x;
        sxh[r][c4 + 1] = (_Float16)v.y;
        sxh[r][c4 + 2] = (_Float16)v.z;
        sxh[r][c4 + 3] = (_Float16)v.w;
    }
    for (int i = t; i < INF_ * HC; i += 256) {
        int k = i >> 6, c = i & 63;
        sWT[c][k] = (_Float16)W[i];
    }
    __syncthreads();
    int w = t >> 6, l = t & 63;
    int lr = l & 15, kg = l >> 4;
    f32x4 acc0 = {0.f,0.f,0.f,0.f}, acc1 = acc0, acc2 = acc0, acc3 = acc0;
#pragma unroll
    for (int kk = 0; kk < 4; ++kk) {
        half8 a = *(half8*)&sxh[w * 16 + lr][kk * 32 + kg * 8];
        half8 b0 = *(half8*)&sWT[0 * 16 + lr][kk * 32 + kg * 8];
        half8 b1 = *(half8*)&sWT[1 * 16 + lr][kk * 32 + kg * 8];
        half8 b2 = *(half8*)&sWT[2 * 16 + lr][kk * 32 + kg * 8];
        half8 b3 = *(half8*)&sWT[3 * 16 + lr][kk * 32 + kg * 8];
        acc0 = __builtin_amdgcn_mfma_f32_16x16x32_f16(a, b0, acc0, 0, 0, 0);
        acc1 = __builtin_amdgcn_mfma_f32_16x16x32_f16(a, b1, acc1, 0, 0, 0);
        acc2 = __builtin_amdgcn_mfma_f32_16x16x32_f16(a, b2, acc2, 0, 0, 0);
        acc3 = __builtin_amdgcn_mfma_f32_16x16x32_f16(a, b3, acc3, 0, 0, 0);
    }
    float attS[4], attD[4];
#pragma unroll
    for (int ct = 0; ct < 4; ++ct) {
        attS[ct] = att_src[ct * 16 + lr];
        attD[ct] = att_dst[ct * 16 + lr];
    }
    int rbase = n0 + w * 16 + kg * 4;
    f32x4 accs[4] = {acc0, acc1, acc2, acc3};
#pragma unroll
    for (int ct = 0; ct < 4; ++ct) {
#pragma unroll
        for (int j = 0; j < 4; ++j) {
            float c = accs[ct][j];
            int node = rbase + j;
            if (node < NN)
                xw16[(size_t)node * HC + ct * 16 + lr] = h2u(c);
            float vs = c * attS[ct];
            float vd = c * attD[ct];
#pragma unroll
            for (int m = 1; m < 16; m <<= 1) {
                vs += __shfl_xor(vs, m);
                vd += __shfl_xor(vd, m);
            }
            if (lr == 0 && node < NN) {
                a_src16[node * HEADS + ct] = h2u(vs);
                a_dst[node * HEADS + ct] = vd;
            }
        }
    }
}

// ---------- pass B: per-dst sort within bucket region + edge_attr sum ----------
__global__ __launch_bounds__(256) void k_binB(const int* __restrict__ ccur,
                                              const uint2* __restrict__ ebuf,
                                              unsigned* __restrict__ esort,
                                              int* __restrict__ deg,
                                              int* __restrict__ offs,
                                              float* __restrict__ easum) {
    __shared__ int lh[256], lcur[256], sd[256];
    __shared__ float lsum[256];
    int t = threadIdx.x;
    int b = blockIdx.x;
    int base = b * CAP;
    int cnt = ccur[b]; if (cnt > CAP) cnt = CAP;
    lh[t] = 0;
    lsum[t] = 0.f;
    __syncthreads();
    for (int i = t; i < cnt; i += 256)
        atomicAdd(&lh[(ebuf[base + i].x >> 16) & 255], 1);
    __syncthreads();
    int v = lh[t];
    sd[t] = v; __syncthreads();
    for (int o = 1; o < 256; o <<= 1) {
        int a = (t >= o) ? sd[t - o] : 0;
        __syncthreads();
        sd[t] += a;
        __syncthreads();
    }
    int ex = sd[t] - v;
    lcur[t] = ex;
    __syncthreads();
    for (int i = t; i < cnt; i += 256) {
        uint2 pk = ebuf[base + i];
        int d = (pk.x >> 16) & 255;
        int p = atomicAdd(&lcur[d], 1);
        atomicAdd(&lsum[d], __uint_as_float(pk.y));
        esort[base + p] = (pk.x & 0xFFFFu) |
                          ((unsigned)h2u(__uint_as_float(pk.y)) << 16);
    }
    __syncthreads();
    int n = (b << 8) + t;
    if (n < NN) { deg[n] = v; offs[n] = base + ex; easum[n] = lsum[t]; }
}

// ---------- K4: gather — 16-edge chunks, LDS handoff, paired phase B ----------
__global__ __launch_bounds__(256) void k_gather(
    const unsigned* __restrict__ esort, const int* __restrict__ offs,
    const int* __restrict__ deg, const float* __restrict__ easum,
    const unsigned short* __restrict__ a_src16, const float* __restrict__ a_dst,
    const unsigned short* __restrict__ xw16,
    const float* __restrict__ W_edge, const float* __restrict__ att_edge,
    const float* __restrict__ bias, float* __restrict__ out) {
    __shared__ __align__(16) float sce[4];
    __shared__ __align__(16) float ldsP[WPB][16][4];
    __shared__ int ldsS[WPB][16];
    int t = threadIdx.x;
    if (t < 4) {
        float s_ = 0.f;
        for (int k = 0; k < OUTF; ++k)
            s_ = fmaf(W_edge[t * OUTF + k], att_edge[t * OUTF + k], s_);
        sce[t] = s_;
    }
    __syncthreads();
    int lane = t & 63;
    int wslot = t >> 6;
    int n = (blockIdx.x << 2) + wslot;   // grid = NN/4 exactly
    int e16 = lane & 15, h = lane >> 4;  // phase A
    int l32 = lane & 31, g = lane >> 5;  // phase B: 2 halves x 32 lanes
    int c2 = l32 * 2, h2 = l32 >> 3;     // 2 channels/lane

    float ceh = sce[h];
    float adh = a_dst[n * HEADS + h];
    int start = offs[n];
    int cnt = deg[n];

    float s = 0.f, a0 = 0.f, a1 = 0.f;

    int nch = (cnt + 15) >> 4;
    for (int ch = 0; ch < nch; ++ch) {
        int base = start + (ch << 4);
        int cc = cnt - (ch << 4); if (cc > 16) cc = 16;
        bool valid = e16 < cc;
        unsigned se = esort[base + e16];   // overread stays inside region (safe)
        int srci = (int)(se & 0xFFFFu);
        float eav = u2f((unsigned short)(se >> 16));
        float asv = u2f(a_src16[srci * HEADS + h]);
        float p = 0.f;
        if (valid) p = __expf(lrelu(asv + adh + eav * ceh));
        ldsP[wslot][e16][h] = p;
        if (h == 0) ldsS[wslot][e16] = srci;
        asm volatile("s_waitcnt lgkmcnt(0)" ::: "memory");
        __builtin_amdgcn_sched_barrier(0);
        // paired phase B: 2 lanes per edge, dword xw loads
#pragma unroll 4
        for (int i = 0; i < cc; i += 2) {
            int ii = i + g;
            if (ii < cc) {
                float pv = ldsP[wslot][ii][h2];
                int si = ldsS[wslot][ii];
                unsigned xv = *(const unsigned*)&xw16[(size_t)si * HC + c2];
                s += pv;
                a0 = fmaf(pv, u2f((unsigned short)(xv & 0xFFFFu)), a0);
                a1 = fmaf(pv, u2f((unsigned short)(xv >> 16)), a1);
            }
        }
        asm volatile("s_waitcnt lgkmcnt(0)" ::: "memory");
        __builtin_amdgcn_sched_barrier(0);
    }
    // combine halves (complementary edges, same channels)
    s  += __shfl_xor(s, 32);
    a0 += __shfl_xor(a0, 32);
    a1 += __shfl_xor(a1, 32);
    // self-loop (fill_value='mean'); both halves compute identically
    float adB = a_dst[n * HEADS + h2];
    float asnB = u2f(a_src16[n * HEADS + h2]);
    float eavm = easum[n] / fmaxf((float)cnt, 1.f);
    float pp = __expf(lrelu(asnB + adB + eavm * sce[h2]));
    unsigned xs = *(const unsigned*)&xw16[(size_t)n * HC + c2];
    s += pp;
    a0 = fmaf(pp, u2f((unsigned short)(xs & 0xFFFFu)), a0);
    a1 = fmaf(pp, u2f((unsigned short)(xs >> 16)), a1);
    if (g == 0) {
        float2 o;
        o.x = fmaxf(a0 / s + bias[c2], 0.f);
        o.y = fmaxf(a1 / s + bias[c2 + 1], 0.f);
        *(float2*)&out[(size_t)n * HC + c2] = o;
    }
}

extern "C" void kernel_launch(void* const* d_in, const int* in_sizes, int n_in,
                              void* d_out, int out_size, void* d_ws, size_t ws_size,
                              hipStream_t stream) {
    const float* x        = (const float*)d_in[0];
    const int*   ei       = (const int*)d_in[1];
    const float* ea       = (const float*)d_in[2];
    const float* W        = (const float*)d_in[3];
    const float* W_edge   = (const float*)d_in[4];
    const float* att_src  = (const float*)d_in[5];
    const float* att_dst  = (const float*)d_in[6];
    const float* att_edge = (const float*)d_in[7];
    const float* bias     = (const float*)d_in[8];
    float* out = (float*)d_out;

    float* ws = (float*)d_ws;
    unsigned short* xw16    = (unsigned short*)ws;              // 64N halves
    uint2* ebuf   = (uint2*)(ws + (size_t)32 * NN);             // NBKT*CAP uint2 (8MB)
    unsigned* esort = (unsigned*)(ebuf + (size_t)NBKT * CAP + 64);  // NBKT*CAP u32 (4MB)
    unsigned short* a_src16 = (unsigned short*)(esort + (size_t)NBKT * CAP + 64);
    float* a_dst  = (float*)(a_src16 + (size_t)HEADS * NN);     // 4N floats
    int*   deg    = (int*)(a_dst + (size_t)HEADS * NN);         // N
    int*   offs   = deg + NN;                                   // N
    float* easum  = (float*)(offs + NN);                        // N
    int*   ccur   = (int*)(easum + NN);                         // NBKT

    hipMemsetAsync(ccur, 0, NBKT * sizeof(int), stream);
    k_binA_xw<<<NBA + NXW, 256, 0, stream>>>(ei, ea, ccur, ebuf,
                                             x, W, att_src, att_dst,
                                             xw16, a_src16, a_dst);
    k_binB<<<NBKT, 256, 0, stream>>>(ccur, ebuf, esort, deg, offs, easum);
    k_gather<<<NN / 4, 256, 0, stream>>>(
        esort, offs, deg, easum, a_src16, a_dst, xw16, W_edge, att_edge, bias, out);
}

// Round 13
// 157.742 us; speedup vs baseline: 1.3283x; 1.0291x over previous
//
#include <hip/hip_runtime.h>
#include <hip/hip_fp16.h>
#include <math.h>

#define NN 50000
#define NE 800000
#define INF_ 128
#define HEADS 4
#define OUTF 16
#define HC 64
#define NEG_SLOPE 0.2f
#define NBKT 196            // buckets of 256 dsts
#define CAP 5120            // region capacity per bucket (mean 4082, 16-sigma slack)
#define CHA 4096            // edges per binA block
#define NBA ((NE + CHA - 1) / CHA)      // 196
#define NXW ((NN + 63) / 64)            // 782
#define WPB 4               // waves per block in gather
#define XPAD 136

typedef _Float16 half8 __attribute__((ext_vector_type(8)));
typedef float f32x4 __attribute__((ext_vector_type(4)));

__device__ __forceinline__ unsigned short h2u(float f) {
    __half h = __float2half(f);
    return *(unsigned short*)&h;
}
__device__ __forceinline__ float u2f(unsigned short u) {
    __half h = *(__half*)&u;
    return __half2float(h);
}
__device__ __forceinline__ float lrelu(float v) {
    return v > 0.f ? v : NEG_SLOPE * v;
}

// ---------- fused: binA (blocks 0..NBA-1)  ||  xw MFMA (blocks NBA..) ----------
__global__ __launch_bounds__(256) void k_binA_xw(
    const int* __restrict__ ei, const float* __restrict__ ea,
    int* __restrict__ ccur, uint2* __restrict__ ebuf,
    const float* __restrict__ x, const float* __restrict__ W,
    const float* __restrict__ att_src, const float* __restrict__ att_dst,
    unsigned short* __restrict__ xw16, unsigned short* __restrict__ a_src16,
    float* __restrict__ a_dst) {
    __shared__ int lh[NBKT], lcur[NBKT];
    __shared__ _Float16 sxh[64][XPAD];
    __shared__ _Float16 sWT[64][XPAD];
    int t = threadIdx.x;
    if (blockIdx.x < NBA) {
        // ================= binA =================
        int e0 = blockIdx.x * CHA;
        int ecnt = NE - e0; if (ecnt > CHA) ecnt = CHA;
        for (int i = t; i < NBKT; i += 256) lh[i] = 0;
        __syncthreads();
        if (ecnt == CHA) {
            int dl[16];
#pragma unroll
            for (int j = 0; j < 16; ++j) {
                dl[j] = ei[NE + e0 + t + j * 256];
                atomicAdd(&lh[dl[j] >> 8], 1);
            }
            __syncthreads();
            for (int i = t; i < NBKT; i += 256)
                lcur[i] = lh[i] ? (i * CAP + atomicAdd(&ccur[i], lh[i])) : 0;
            __syncthreads();
#pragma unroll
            for (int j = 0; j < 16; ++j) {
                int e = e0 + t + j * 256;
                int dst = dl[j];
                int b = dst >> 8;
                int p = atomicAdd(&lcur[b], 1);
                if (p < (b + 1) * CAP) {
                    uint2 pk;
                    pk.x = (unsigned)ei[e] | ((unsigned)(dst & 255) << 16);
                    pk.y = __float_as_uint(ea[e]);
                    ebuf[p] = pk;
                }
            }
        } else {
            for (int i = t; i < ecnt; i += 256)
                atomicAdd(&lh[ei[NE + e0 + i] >> 8], 1);
            __syncthreads();
            for (int i = t; i < NBKT; i += 256)
                lcur[i] = lh[i] ? (i * CAP + atomicAdd(&ccur[i], lh[i])) : 0;
            __syncthreads();
            for (int i = t; i < ecnt; i += 256) {
                int e = e0 + i;
                int dst = ei[NE + e];
                int b = dst >> 8;
                int p = atomicAdd(&lcur[b], 1);
                if (p < (b + 1) * CAP) {
                    uint2 pk;
                    pk.x = (unsigned)ei[e] | ((unsigned)(dst & 255) << 16);
                    pk.y = __float_as_uint(ea[e]);
                    ebuf[p] = pk;
                }
            }
        }
        return;
    }
    // ================= xw (MFMA) =================
    int n0 = (blockIdx.x - NBA) * 64;
    for (int i = t; i < 64 * 32; i += 256) {
        int r = i >> 5, c4 = (i & 31) * 4;
        int n = n0 + r;
        float4 v = (n < NN) ? *(const float4*)&x[(size_t)n * INF_ + c4]
                            : make_float4(0.f, 0.f, 0.f, 0.f);
        sxh[r][c4 + 0] = (_Float16)v.x;
        sxh[r][c4 + 1] = (_Float16)v.y;
        sxh[r][c4 + 2] = (_Float16)v.z;
        sxh[r][c4 + 3] = (_Float16)v.w;
    }
    for (int i = t; i < INF_ * HC; i += 256) {
        int k = i >> 6, c = i & 63;
        sWT[c][k] = (_Float16)W[i];
    }
    __syncthreads();
    int w = t >> 6, l = t & 63;
    int lr = l & 15, kg = l >> 4;
    f32x4 acc0 = {0.f,0.f,0.f,0.f}, acc1 = acc0, acc2 = acc0, acc3 = acc0;
#pragma unroll
    for (int kk = 0; kk < 4; ++kk) {
        half8 a = *(half8*)&sxh[w * 16 + lr][kk * 32 + kg * 8];
        half8 b0 = *(half8*)&sWT[0 * 16 + lr][kk * 32 + kg * 8];
        half8 b1 = *(half8*)&sWT[1 * 16 + lr][kk * 32 + kg * 8];
        half8 b2 = *(half8*)&sWT[2 * 16 + lr][kk * 32 + kg * 8];
        half8 b3 = *(half8*)&sWT[3 * 16 + lr][kk * 32 + kg * 8];
        acc0 = __builtin_amdgcn_mfma_f32_16x16x32_f16(a, b0, acc0, 0, 0, 0);
        acc1 = __builtin_amdgcn_mfma_f32_16x16x32_f16(a, b1, acc1, 0, 0, 0);
        acc2 = __builtin_amdgcn_mfma_f32_16x16x32_f16(a, b2, acc2, 0, 0, 0);
        acc3 = __builtin_amdgcn_mfma_f32_16x16x32_f16(a, b3, acc3, 0, 0, 0);
    }
    float attS[4], attD[4];
#pragma unroll
    for (int ct = 0; ct < 4; ++ct) {
        attS[ct] = att_src[ct * 16 + lr];
        attD[ct] = att_dst[ct * 16 + lr];
    }
    int rbase = n0 + w * 16 + kg * 4;
    f32x4 accs[4] = {acc0, acc1, acc2, acc3};
#pragma unroll
    for (int ct = 0; ct < 4; ++ct) {
#pragma unroll
        for (int j = 0; j < 4; ++j) {
            float c = accs[ct][j];
            int node = rbase + j;
            if (node < NN)
                xw16[(size_t)node * HC + ct * 16 + lr] = h2u(c);
            float vs = c * attS[ct];
            float vd = c * attD[ct];
#pragma unroll
            for (int m = 1; m < 16; m <<= 1) {
                vs += __shfl_xor(vs, m);
                vd += __shfl_xor(vd, m);
            }
            if (lr == 0 && node < NN) {
                a_src16[node * HEADS + ct] = h2u(vs);
                a_dst[node * HEADS + ct] = vd;
            }
        }
    }
}

// ---------- pass B: per-dst sort within bucket region + edge_attr sum ----------
__global__ __launch_bounds__(256) void k_binB(const int* __restrict__ ccur,
                                              const uint2* __restrict__ ebuf,
                                              unsigned* __restrict__ esort,
                                              int* __restrict__ deg,
                                              int* __restrict__ offs,
                                              float* __restrict__ easum) {
    __shared__ int lh[256], lcur[256], sd[256];
    __shared__ float lsum[256];
    int t = threadIdx.x;
    int b = blockIdx.x;
    int base = b * CAP;
    int cnt = ccur[b]; if (cnt > CAP) cnt = CAP;
    lh[t] = 0;
    lsum[t] = 0.f;
    __syncthreads();
    for (int i = t; i < cnt; i += 256)
        atomicAdd(&lh[(ebuf[base + i].x >> 16) & 255], 1);
    __syncthreads();
    int v = lh[t];
    sd[t] = v; __syncthreads();
    for (int o = 1; o < 256; o <<= 1) {
        int a = (t >= o) ? sd[t - o] : 0;
        __syncthreads();
        sd[t] += a;
        __syncthreads();
    }
    int ex = sd[t] - v;
    lcur[t] = ex;
    __syncthreads();
    for (int i = t; i < cnt; i += 256) {
        uint2 pk = ebuf[base + i];
        int d = (pk.x >> 16) & 255;
        int p = atomicAdd(&lcur[d], 1);
        atomicAdd(&lsum[d], __uint_as_float(pk.y));
        esort[base + p] = (pk.x & 0xFFFFu) |
                          ((unsigned)h2u(__uint_as_float(pk.y)) << 16);
    }
    __syncthreads();
    int n = (b << 8) + t;
    if (n < NN) { deg[n] = v; offs[n] = base + ex; easum[n] = lsum[t]; }
}

// ---------- K4: gather — 16-edge chunks, LDS handoff, serial phase B (R9) ----------
__global__ __launch_bounds__(256) void k_gather(
    const unsigned* __restrict__ esort, const int* __restrict__ offs,
    const int* __restrict__ deg, const float* __restrict__ easum,
    const unsigned short* __restrict__ a_src16, const float* __restrict__ a_dst,
    const unsigned short* __restrict__ xw16,
    const float* __restrict__ W_edge, const float* __restrict__ att_edge,
    const float* __restrict__ bias, float* __restrict__ out) {
    __shared__ __align__(16) float sce[4];
    __shared__ __align__(16) float ldsP[WPB][16][4];
    __shared__ int ldsS[WPB][16];
    int t = threadIdx.x;
    if (t < 4) {
        float s_ = 0.f;
        for (int k = 0; k < OUTF; ++k)
            s_ = fmaf(W_edge[t * OUTF + k], att_edge[t * OUTF + k], s_);
        sce[t] = s_;
    }
    __syncthreads();
    int lane = t & 63;
    int wslot = t >> 6;
    int n = (blockIdx.x << 2) + wslot;   // grid = NN/4 exactly
    int e16 = lane & 15;
    int h = lane >> 4;

    float ceh = sce[h];
    float adh = a_dst[n * HEADS + h];
    int start = offs[n];
    int cnt = deg[n];

    float s = 0.f, acc = 0.f;

    int nch = (cnt + 15) >> 4;
    for (int ch = 0; ch < nch; ++ch) {
        int base = start + (ch << 4);
        int cc = cnt - (ch << 4); if (cc > 16) cc = 16;
        bool valid = e16 < cc;
        unsigned se = esort[base + e16];   // overread stays inside region (safe)
        int srci = (int)(se & 0xFFFFu);
        float eav = u2f((unsigned short)(se >> 16));
        float asv = u2f(a_src16[srci * HEADS + h]);
        float p = 0.f;
        if (valid) p = __expf(lrelu(asv + adh + eav * ceh));
        ldsP[wslot][e16][h] = p;
        if (h == 0) ldsS[wslot][e16] = srci;
        asm volatile("s_waitcnt lgkmcnt(0)" ::: "memory");
        __builtin_amdgcn_sched_barrier(0);
        // phase B: lane = channel, serial accumulate (broadcast LDS reads)
#pragma unroll 4
        for (int i = 0; i < cc; ++i) {
            float pv = ldsP[wslot][i][h];
            int si = ldsS[wslot][i];
            float xv = u2f(xw16[(size_t)si * HC + lane]);
            s += pv;
            acc = fmaf(pv, xv, acc);
        }
        asm volatile("s_waitcnt lgkmcnt(0)" ::: "memory");
        __builtin_amdgcn_sched_barrier(0);
    }
    // self-loop (fill_value='mean')
    float asn = u2f(a_src16[n * HEADS + h]);
    float eavm = easum[n] / fmaxf((float)cnt, 1.f);
    float p = __expf(lrelu(asn + adh + eavm * ceh));
    float xself = u2f(xw16[(size_t)n * HC + lane]);
    s += p;
    acc = fmaf(p, xself, acc);
    out[(size_t)n * HC + lane] = fmaxf(acc / s + bias[lane], 0.f);
}

extern "C" void kernel_launch(void* const* d_in, const int* in_sizes, int n_in,
                              void* d_out, int out_size, void* d_ws, size_t ws_size,
                              hipStream_t stream) {
    const float* x        = (const float*)d_in[0];
    const int*   ei       = (const int*)d_in[1];
    const float* ea       = (const float*)d_in[2];
    const float* W        = (const float*)d_in[3];
    const float* W_edge   = (const float*)d_in[4];
    const float* att_src  = (const float*)d_in[5];
    const float* att_dst  = (const float*)d_in[6];
    const float* att_edge = (const float*)d_in[7];
    const float* bias     = (const float*)d_in[8];
    float* out = (float*)d_out;

    float* ws = (float*)d_ws;
    unsigned short* xw16    = (unsigned short*)ws;              // 64N halves
    uint2* ebuf   = (uint2*)(ws + (size_t)32 * NN);             // NBKT*CAP uint2 (8MB)
    unsigned* esort = (unsigned*)(ebuf + (size_t)NBKT * CAP + 64);  // NBKT*CAP u32 (4MB)
    unsigned short* a_src16 = (unsigned short*)(esort + (size_t)NBKT * CAP + 64);
    float* a_dst  = (float*)(a_src16 + (size_t)HEADS * NN);     // 4N floats
    int*   deg    = (int*)(a_dst + (size_t)HEADS * NN);         // N
    int*   offs   = deg + NN;                                   // N
    float* easum  = (float*)(offs + NN);                        // N
    int*   ccur   = (int*)(easum + NN);                         // NBKT

    hipMemsetAsync(ccur, 0, NBKT * sizeof(int), stream);
    k_binA_xw<<<NBA + NXW, 256, 0, stream>>>(ei, ea, ccur, ebuf,
                                             x, W, att_src, att_dst,
                                             xw16, a_src16, a_dst);
    k_binB<<<NBKT, 256, 0, stream>>>(ccur, ebuf, esort, deg, offs, easum);
    k_gather<<<NN / 4, 256, 0, stream>>>(
        esort, offs, deg, easum, a_src16, a_dst, xw16, W_edge, att_edge, bias, out);
}